// Round 3
// baseline (109.053 us; speedup 1.0000x reference)
//
#include <hip/hip_runtime.h>
#include <hip/hip_bf16.h>

#define IMG 256
#define NG 1024
constexpr float PIX   = 1.0f / 256.0f;
constexpr float TTH   = 0.0001f;
constexpr float ACLIP = 0.99f;
constexpr float NEGHALF_LOG2E = -0.72134752044f;   // -0.5 * log2(e)

// ws layout (floats):
//   [0, 12288)      params[NG][12] = {mx,my,s00,soff,s11,alpha,cr,cg,cb,pad,pad,pad}
//                   (s** = inv-cov premultiplied by -0.5*log2e -> a_eff = alpha*exp2(quad))
//   [12288, 16384)  bbox SoA: bmx[NG], bmy[NG], brx[NG], bry[NG]

__global__ __launch_bounds__(256)
void gs_prep(const float* __restrict__ mean, const float* __restrict__ cov,
             const float* __restrict__ color, const float* __restrict__ alpha,
             const float* __restrict__ depth, float* __restrict__ ws)
{
    __shared__ float sdepth[NG];
    const int tid = threadIdx.x;
    const int t   = blockIdx.x * 256 + tid;       // gaussian id (4 blocks x 256)

    for (int i = tid; i < NG; i += 256) sdepth[i] = depth[i];
    __syncthreads();

    const float d = sdepth[t];
    int rank = 0;
    const float4* s4 = (const float4*)sdepth;
    #pragma unroll 4
    for (int j4 = 0; j4 < NG / 4; ++j4) {
        const float4 dj = s4[j4];                 // broadcast read
        const int j = j4 * 4;
        rank += (dj.x < d) || (dj.x == d && (j + 0) < t);
        rank += (dj.y < d) || (dj.y == d && (j + 1) < t);
        rank += (dj.z < d) || (dj.z == d && (j + 2) < t);
        rank += (dj.w < d) || (dj.w == d && (j + 3) < t);
    }

    const float a  = cov[t * 4 + 0];
    const float b  = cov[t * 4 + 1];
    const float c  = cov[t * 4 + 2];
    const float dd = cov[t * 4 + 3];
    const float det    = a * dd - b * c;
    const float inv00  = dd / det;
    const float inv11  = a / det;
    const float invoff = -(b + c) / det;

    const float al = alpha[t];
    // cull cutoff: a_eff = al*exp(-q/2) < 1e-6  ->  q > 2*ln(al*1e6)
    float qcut = 2.0f * __logf(al * 1.0e6f + 1.0e-30f);
    qcut = fminf(fmaxf(qcut, 0.0f), 28.0f);
    const float rx = sqrtf(qcut * fmaxf(a,  0.0f));   // sqrt(q*Sxx)
    const float ry = sqrtf(qcut * fmaxf(dd, 0.0f));

    const float mx = mean[t * 2 + 0];
    const float my = mean[t * 2 + 1];

    float* o = ws + rank * 12;
    o[0] = mx;
    o[1] = my;
    o[2] = inv00  * NEGHALF_LOG2E;
    o[3] = invoff * NEGHALF_LOG2E;
    o[4] = inv11  * NEGHALF_LOG2E;
    o[5] = al;
    o[6] = color[t * 3 + 0];
    o[7] = color[t * 3 + 1];
    o[8] = color[t * 3 + 2];
    o[9] = 0.0f; o[10] = 0.0f; o[11] = 0.0f;

    float* bb = ws + NG * 12;
    bb[rank]          = mx;
    bb[NG + rank]     = my;
    bb[2 * NG + rank] = rx;
    bb[3 * NG + rank] = ry;
}

__global__ __launch_bounds__(256)
void gs_render(const float* __restrict__ ws, const float* __restrict__ bg,
               const float* __restrict__ topleft, float* __restrict__ out)
{
    __shared__ float4 sg[NG * 3];                 // 48 KiB params
    __shared__ float  sbx[NG], sby[NG], srx[NG], sry[NG];  // 16 KiB bbox SoA
    const int tid = threadIdx.x;

    const float4* p4 = (const float4*)ws;
    #pragma unroll
    for (int i = 0; i < 12; ++i)
        sg[tid + i * 256] = p4[tid + i * 256];
    const float4* b4 = (const float4*)(ws + NG * 12);
    ((float4*)sbx)[tid] = b4[tid];
    ((float4*)sby)[tid] = b4[256 + tid];
    ((float4*)srx)[tid] = b4[512 + tid];
    ((float4*)sry)[tid] = b4[768 + tid];
    __syncthreads();

    const int wave = tid >> 6;
    const int lane = tid & 63;
    const int tile = blockIdx.x;                  // 256 tiles of 16x16 px
    // each wave owns an 8x8 sub-tile
    const int tx = (tile & 15) * 16 + (wave & 1) * 8;
    const int ty = (tile >> 4) * 16 + (wave >> 1) * 8;
    const int col = tx + (lane & 7);
    const int row = ty + (lane >> 3);
    const float tl0 = topleft[0], tl1 = topleft[1];
    const float px = ((float)col + 0.5f) * PIX - tl0;
    const float py = ((float)row + 0.5f) * PIX - tl1;
    const float cx = ((float)tx + 4.0f) * PIX - tl0;   // center of 8x8 pixel centers
    const float cy = ((float)ty + 4.0f) * PIX - tl1;
    const float hw = 3.5f * PIX;

    float T = 1.0f, r = 0.0f, g = 0.0f, b = 0.0f;

    for (int c = 0; c < NG / 64; ++c) {
        if (__all(T <= TTH)) break;               // whole wave saturated

        const int gi = c * 64 + lane;             // conflict-free SoA reads
        const bool hit = (fabsf(sbx[gi] - cx) <= srx[gi] + hw) &&
                         (fabsf(sby[gi] - cy) <= sry[gi] + hw);
        unsigned long long mask = __ballot(hit);  // wave-uniform
        if (!mask) continue;

        // software-pipelined bit loop (prefetch next gaussian's LDS reads)
        int j = __ffsll(mask) - 1; mask &= mask - 1;
        int base = (c * 64 + j) * 3;
        float4 a0 = sg[base];                     // mx,my,s00,soff
        float4 a1 = sg[base + 1];                 // s11,alpha,cr,cg
        float  cb = sg[base + 2].x;               // cb

        for (;;) {
            const bool more = (mask != 0);        // wave-uniform branch
            float4 n0, n1; float ncb = 0.0f;
            if (more) {
                const int jn = __ffsll(mask) - 1; mask &= mask - 1;
                const int nb = (c * 64 + jn) * 3;
                n0 = sg[nb]; n1 = sg[nb + 1]; ncb = sg[nb + 2].x;
            }

            const float dx = px - a0.x;
            const float dy = py - a0.y;
            const float q  = dx * (a0.z * dx + a0.w * dy) + a1.x * dy * dy;
            const float e  = exp2f(q);            // = exp(-0.5*quad)
            const float aeff = fminf(a1.y * e, ACLIP);
            const float w  = aeff * T;            // ungated: tail error <= 1e-4
            r = fmaf(w, a1.z, r);
            g = fmaf(w, a1.w, g);
            b = fmaf(w, cb, b);
            T = T - w;                            // == T*(1-aeff)

            if (!more) break;
            a0 = n0; a1 = n1; cb = ncb;
        }
    }

    const int p = row * 256 + col;
    const float* bgp = bg + p * 3;
    float* op = out + p * 3;
    op[0] = r + T * bgp[0];
    op[1] = g + T * bgp[1];
    op[2] = b + T * bgp[2];
}

extern "C" void kernel_launch(void* const* d_in, const int* in_sizes, int n_in,
                              void* d_out, int out_size, void* d_ws, size_t ws_size,
                              hipStream_t stream) {
    const float* mean    = (const float*)d_in[0];
    const float* cov     = (const float*)d_in[1];
    const float* color   = (const float*)d_in[2];
    const float* alpha   = (const float*)d_in[3];
    const float* depth   = (const float*)d_in[4];
    const float* bg      = (const float*)d_in[5];
    const float* topleft = (const float*)d_in[6];
    float* out = (float*)d_out;
    float* ws  = (float*)d_ws;                    // 64 KiB used

    gs_prep<<<4, 256, 0, stream>>>(mean, cov, color, alpha, depth, ws);
    gs_render<<<IMG * IMG / 256, 256, 0, stream>>>(ws, bg, topleft, out);
}